// Round 8
// baseline (75.712 us; speedup 1.0000x reference)
//
#include <hip/hip_runtime.h>

// NPS: out = (1/N) * sum_pixels min_k sqrt( sum_c ((x_c - p_kc) + 1e-6)^2 + 1e-6 )
// Identity: with y_c = x_c + 1e-6,
//   d_k = (|y|^2 + 1e-6) + (|p_k|^2 - 2 y.p_k)
// Precompute q_k = (-2*p_k, |p_k|^2) in LDS -> inner loop is 3 fma + 1 min
// per (pixel,color); one sqrt per pixel.
//
// R11: packed-fp32 inner loop. gfx950 has v_pk_fma_f32 (2 fma/instr,
// FeaturePackedFP32Ops, gfx90a+). Process pixel PAIRS as
// ext_vector_type(2) floats with __builtin_elementwise_fma so LLVM can
// select packed FMAs: inner loop 720 fma + 240 min = 960 scalar instrs
// -> 360 pk_fma + 240 min = 600 (-37%). Worst case compiler scalarizes
// (neutral). No v_pk_min_f32 exists -> mins stay scalar.
// NT loads reverted (R10: unproven, possibly -1.2 us regression).
//
// Session model (R5-R10): timed window = ~44 us ws poison fill (harness,
// uncontrollable) + ~20 us harness small resets/gaps + ~10 us our two
// dispatches. Fusion is a measured dead end: chain=74.2 / coop=199 (spin)
// / fused+memset=87.7 / fused+flags=79.5 — cross-XCD completion handshake
// costs more than the k2 launch it replaces. Kernel-boundary coherence is
// the cheapest cross-XCD sync. R7: 16 px/thread spills to scratch — keep 8.
// k1 = 1024 blk x 256 thr x 8 px (48 VGPR class config).

#define NPS_HW   (512 * 512)        // 262144 = 2^18
#define NPS_NCOL 30
#define NPS_NBLK 1024               // k1 grid: 4 blocks/CU
#define NPS_INV_TOTAL (1.0f / 6291456.0f)   // 1 / (B*C*H*W)

typedef float v2f __attribute__((ext_vector_type(2)));
typedef float vf4 __attribute__((ext_vector_type(4)));

__global__ __launch_bounds__(256) void nps_partial_kernel(
    const float* __restrict__ patch,   // (B, 3, H, W) planar fp32
    const float* __restrict__ prt,     // (30, 3) fp32
    float* __restrict__ partial)       // (NPS_NBLK,) in d_ws
{
    __shared__ float4 sq[NPS_NCOL];    // {-2p0, -2p1, -2p2, |p|^2}
    __shared__ float wave_part[4];

    const int t = threadIdx.x;
    if (t < NPS_NCOL) {
        float p0 = prt[t * 3 + 0];
        float p1 = prt[t * 3 + 1];
        float p2 = prt[t * 3 + 2];
        sq[t] = make_float4(-2.0f * p0, -2.0f * p1, -2.0f * p2,
                            fmaf(p0, p0, fmaf(p1, p1, p2 * p2)));
    }
    __syncthreads();

    // 8 consecutive pixels per thread (HW = 2^18 is a multiple of 8,
    // so a thread never crosses a batch boundary)
    const int gid = blockIdx.x * 256 + t;          // 0 .. 262143
    const int pix = gid << 3;                      // first pixel (b*HW + hw)
    const int b   = pix >> 18;                     // / NPS_HW
    const int hw  = pix & (NPS_HW - 1);

    const float* base = patch + (size_t)b * 3 * NPS_HW + hw;

    // 6 dwordx4 loads, all issued up front for max MLP
    const vf4 xa0 = *(const vf4*)(base);
    const vf4 xb0 = *(const vf4*)(base + 4);
    const vf4 xa1 = *(const vf4*)(base + NPS_HW);
    const vf4 xb1 = *(const vf4*)(base + NPS_HW + 4);
    const vf4 xa2 = *(const vf4*)(base + 2 * NPS_HW);
    const vf4 xb2 = *(const vf4*)(base + 2 * NPS_HW + 4);

    // pixel pairs as v2f -> <2 x float> IR -> v_pk_* selection
    const v2f eps2 = { 1e-6f, 1e-6f };
    v2f Y0[4] = { { xa0.x, xa0.y }, { xa0.z, xa0.w }, { xb0.x, xb0.y }, { xb0.z, xb0.w } };
    v2f Y1[4] = { { xa1.x, xa1.y }, { xa1.z, xa1.w }, { xb1.x, xb1.y }, { xb1.z, xb1.w } };
    v2f Y2[4] = { { xa2.x, xa2.y }, { xa2.z, xa2.w }, { xb2.x, xb2.y }, { xb2.z, xb2.w } };
#pragma unroll
    for (int j = 0; j < 4; ++j) {
        Y0[j] += eps2; Y1[j] += eps2; Y2[j] += eps2;
    }

    v2f HH[4], M[4];
#pragma unroll
    for (int j = 0; j < 4; ++j) {
        HH[j] = __builtin_elementwise_fma(Y0[j], Y0[j],
                __builtin_elementwise_fma(Y1[j], Y1[j],
                __builtin_elementwise_fma(Y2[j], Y2[j], eps2)));
        M[j]  = (v2f){ 1e30f, 1e30f };
    }

#pragma unroll 6
    for (int k = 0; k < NPS_NCOL; ++k) {
        const float4 q = sq[k];
        const v2f qx = { q.x, q.x };
        const v2f qy = { q.y, q.y };
        const v2f qz = { q.z, q.z };
        const v2f qw = { q.w, q.w };
#pragma unroll
        for (int j = 0; j < 4; ++j) {
            // |p|^2 - 2 y.p for two pixels: 3 v_pk_fma_f32
            v2f u = __builtin_elementwise_fma(Y0[j], qx,
                    __builtin_elementwise_fma(Y1[j], qy,
                    __builtin_elementwise_fma(Y2[j], qz, qw)));
            M[j] = __builtin_elementwise_min(M[j], u);
        }
    }

    float s = 0.0f;
#pragma unroll
    for (int j = 0; j < 4; ++j) {
        const v2f d = HH[j] + M[j];
        s += sqrtf(fmaxf(d.x, 0.0f));
        s += sqrtf(fmaxf(d.y, 0.0f));
    }

    // wave (64-lane) reduction
#pragma unroll
    for (int off = 32; off > 0; off >>= 1) {
        s += __shfl_down(s, off);
    }
    const int lane = t & 63;
    const int w    = t >> 6;
    if (lane == 0) wave_part[w] = s;
    __syncthreads();
    if (t == 0) {
        // plain store: kernel boundary gives cross-XCD coherence for k2
        partial[blockIdx.x] = (wave_part[0] + wave_part[1]) + (wave_part[2] + wave_part[3]);
    }
}

__global__ __launch_bounds__(256) void nps_final_kernel(
    const float* __restrict__ partial,  // (NPS_NBLK,)
    float* __restrict__ out)            // (1,)
{
    __shared__ float wave_part[4];
    const int t = threadIdx.x;

    // fixed-order read of 1024 partials: bit-stable across replays
    float v = (partial[t] + partial[t + 256]) + (partial[t + 512] + partial[t + 768]);
#pragma unroll
    for (int off = 32; off > 0; off >>= 1) {
        v += __shfl_down(v, off);
    }
    const int lane = t & 63;
    const int w    = t >> 6;
    if (lane == 0) wave_part[w] = v;
    __syncthreads();
    if (t == 0) {
        out[0] = ((wave_part[0] + wave_part[1]) + (wave_part[2] + wave_part[3])) * NPS_INV_TOTAL;
    }
}

extern "C" void kernel_launch(void* const* d_in, const int* in_sizes, int n_in,
                              void* d_out, int out_size, void* d_ws, size_t ws_size,
                              hipStream_t stream) {
    const float* patch = (const float*)d_in[0];   // 8*3*512*512 fp32
    const float* prt   = (const float*)d_in[1];   // 30*3 fp32
    float* out     = (float*)d_out;               // 1 fp32
    float* partial = (float*)d_ws;                // 1024 fp32 scratch

    nps_partial_kernel<<<NPS_NBLK, 256, 0, stream>>>(patch, prt, partial);
    nps_final_kernel<<<1, 256, 0, stream>>>(partial, out);
}